// Round 5
// baseline (543.603 us; speedup 1.0000x reference)
//
#include <hip/hip_runtime.h>
#include <math.h>

#define N_NODES 50000
#define N_EDGES 400000
#define IN_F 256
#define OUT_F 64
#define ED_F 64
#define NH 4
#define SCAN_NB ((N_NODES + 255) / 256)

using f16x8 = __attribute__((ext_vector_type(8))) _Float16;
using f32x4 = __attribute__((ext_vector_type(4))) float;

// block 0: u[h][f] = sum_g W_eatt[h][f][g]*We[h][g]; c[h] = b_att[h] + b_eatt[h].We[h]
// blocks 1..32: Wfcfrag (f16, MFMA b-frag order), blocks 33..40: Wefrag
__global__ __launch_bounds__(256) void prep_kernel(
    const float* __restrict__ W_att, const float* __restrict__ b_att,
    const float* __restrict__ W_eatt, const float* __restrict__ b_eatt,
    const float* __restrict__ W_fc, const float* __restrict__ W_edge,
    float* __restrict__ u, float* __restrict__ c,
    _Float16* __restrict__ Wfcfrag, _Float16* __restrict__ Wefrag)
{
    const int b = blockIdx.x, t = threadIdx.x;
    if (b == 0) {
        int h = t >> 6, f = t & 63;
        const float* We = W_att + h * (2 * OUT_F + ED_F) + 2 * OUT_F;
        float s = 0.f;
        for (int g = 0; g < ED_F; g++) s += W_eatt[(h * ED_F + f) * ED_F + g] * We[g];
        u[t] = s;
        if (f == 0) {
            float cc = b_att[h];
            for (int g = 0; g < ED_F; g++) cc += b_eatt[h * ED_F + g] * We[g];
            c[h] = cc;
        }
    } else if (b <= 32) {
        // b_frag[lane][j] = B[k=quad*8+j][n=lane&15], B = W_fc[h] (256x64)
        int idx = b - 1;
        int h = idx >> 3, kt = idx & 7;
        int lane = t & 63, nt = t >> 6;
        int q = lane >> 4, l15 = lane & 15;
        f16x8 w;
#pragma unroll
        for (int j = 0; j < 8; j++) {
            int k = kt * 32 + q * 8 + j;
            int o = nt * 16 + l15;
            w[j] = (_Float16)W_fc[((size_t)h * IN_F + k) * OUT_F + o];
        }
        *(f16x8*)&Wfcfrag[(size_t)(((h * 8 + kt) * 4 + nt) * 64 + lane) * 8] = w;
    } else {
        int idx = b - 33;
        int h = idx >> 1, kt = idx & 1;
        int lane = t & 63, nt = t >> 6;
        int q = lane >> 4, l15 = lane & 15;
        f16x8 w;
#pragma unroll
        for (int j = 0; j < 8; j++) {
            int k = kt * 32 + q * 8 + j;
            int o = nt * 16 + l15;
            w[j] = (_Float16)W_edge[((size_t)h * ED_F + k) * OUT_F + o];
        }
        *(f16x8*)&Wefrag[(size_t)(((h * 2 + kt) * 4 + nt) * 64 + lane) * 8] = w;
    }
}

// z[h][n][o] = x@W_fc + b_fc, f16 MFMA 16x16x32. Block: 64 nodes, 4 waves = 4 heads.
// Fused epilogue: a_i[h][n] = z.Wi, a_j[h][n] = z.Wj (computed from fp32 acc).
__global__ __launch_bounds__(256) void z_gemm(
    const float* __restrict__ x, const _Float16* __restrict__ Wfcfrag,
    const float* __restrict__ b_fc, const float* __restrict__ W_att,
    _Float16* __restrict__ zb, float* __restrict__ a_i, float* __restrict__ a_j)
{
    __shared__ _Float16 aLDS[32 * 64 * 8];   // 32 chunks(kt,quad) x 64 nodes x 8 f16 = 32KB
    const int t = threadIdx.x;
    const int n0 = blockIdx.x * 64;
    const int lane = t & 63, h = t >> 6;
    const int q = lane >> 4, l15 = lane & 15;

    // stage x tile (64 nodes x 256 k) fp32 -> f16 frag-order LDS
    {
        const int m = t >> 2, qq = t & 3;
        const int n = n0 + m;
#pragma unroll
        for (int p = 0; p < 4; p++) {
            float4 v4[4];
            if (n < N_NODES) {
                const float4* xp = (const float4*)(x + (size_t)n * IN_F + p * 64 + qq * 16);
#pragma unroll
                for (int k = 0; k < 4; k++) v4[k] = xp[k];
            } else {
#pragma unroll
                for (int k = 0; k < 4; k++) v4[k] = make_float4(0.f, 0.f, 0.f, 0.f);
            }
            const float* vv = (const float*)v4;
#pragma unroll
            for (int i = 0; i < 2; i++) {
                int c8 = p * 8 + qq * 2 + i;
                f16x8 w;
#pragma unroll
                for (int j = 0; j < 8; j++) w[j] = (_Float16)vv[i * 8 + j];
                *(f16x8*)&aLDS[(c8 * 64 + m) * 8] = w;
            }
        }
    }
    __syncthreads();

    f32x4 acc[4][4];
#pragma unroll
    for (int mt = 0; mt < 4; mt++)
#pragma unroll
        for (int nt = 0; nt < 4; nt++) acc[mt][nt] = (f32x4)0.f;

    for (int kt = 0; kt < 8; kt++) {
        f16x8 bfr[4];
#pragma unroll
        for (int nt = 0; nt < 4; nt++)
            bfr[nt] = *(const f16x8*)&Wfcfrag[(size_t)(((h * 8 + kt) * 4 + nt) * 64 + lane) * 8];
        f16x8 afr[4];
#pragma unroll
        for (int mt = 0; mt < 4; mt++)
            afr[mt] = *(f16x8*)&aLDS[((kt * 4 + q) * 64 + mt * 16 + l15) * 8];
#pragma unroll
        for (int mt = 0; mt < 4; mt++)
#pragma unroll
            for (int nt = 0; nt < 4; nt++)
                acc[mt][nt] = __builtin_amdgcn_mfma_f32_16x16x32_f16(afr[mt], bfr[nt], acc[mt][nt], 0, 0, 0);
    }

    float bfc[4], wiv[4], wjv[4];
#pragma unroll
    for (int nt = 0; nt < 4; nt++) {
        bfc[nt] = b_fc[h * OUT_F + nt * 16 + l15];
        wiv[nt] = W_att[h * 192 + nt * 16 + l15];
        wjv[nt] = W_att[h * 192 + 64 + nt * 16 + l15];
    }

    // C/D layout: col = lane&15, row = quad*4 + reg
#pragma unroll
    for (int mt = 0; mt < 4; mt++) {
#pragma unroll
        for (int r = 0; r < 4; r++) {
            const int node = n0 + mt * 16 + q * 4 + r;
            float zv[4];
            float pi = 0.f, pj = 0.f;
#pragma unroll
            for (int nt = 0; nt < 4; nt++) {
                zv[nt] = acc[mt][nt][r] + bfc[nt];
                pi += zv[nt] * wiv[nt];
                pj += zv[nt] * wjv[nt];
            }
            // reduce over the 16 l15 lanes (same q group -> same node)
#pragma unroll
            for (int m = 8; m; m >>= 1) {
                pi += __shfl_xor(pi, m, 64);
                pj += __shfl_xor(pj, m, 64);
            }
            if (node < N_NODES) {
                _Float16* zrow = zb + ((size_t)h * N_NODES + node) * OUT_F;
#pragma unroll
                for (int nt = 0; nt < 4; nt++)
                    zrow[nt * 16 + l15] = (_Float16)zv[nt];
                if (l15 == 0) {
                    a_i[h * N_NODES + node] = pi;
                    a_j[h * N_NODES + node] = pj;
                }
            }
        }
    }
}

// --- counting-sort by dst -------------------------------------------------

__global__ __launch_bounds__(256) void hist_kernel(
    const int* __restrict__ edge_index, int* __restrict__ deg)
{
    const int e = blockIdx.x * 256 + threadIdx.x;
    if (e < N_EDGES) atomicAdd(&deg[edge_index[N_EDGES + e]], 1);
}

// hierarchical scan phase 1: per-block exclusive scan + block totals
__global__ __launch_bounds__(256) void scan1_kernel(
    const int* __restrict__ deg, int* __restrict__ row_ptr, int* __restrict__ bsum)
{
    __shared__ int wsum[4];
    const int t = threadIdx.x, lane = t & 63, w = t >> 6;
    const int idx = blockIdx.x * 256 + t;
    int v = (idx < N_NODES) ? deg[idx] : 0;
    int x = v;
#pragma unroll
    for (int off = 1; off < 64; off <<= 1) {
        int y = __shfl_up(x, off, 64);
        if (lane >= off) x += y;
    }
    if (lane == 63) wsum[w] = x;
    __syncthreads();
    int woff = 0;
#pragma unroll
    for (int i = 0; i < 4; i++) if (i < w) woff += wsum[i];
    if (idx < N_NODES) row_ptr[idx] = woff + x - v;
    if (t == 255) bsum[blockIdx.x] = woff + x;
}

// phase 2: single block scans the <=256 block totals in place (exclusive)
__global__ __launch_bounds__(256) void scan2_kernel(int* __restrict__ bsum)
{
    __shared__ int wsum[4];
    const int t = threadIdx.x, lane = t & 63, w = t >> 6;
    int v = (t < SCAN_NB) ? bsum[t] : 0;
    int x = v;
#pragma unroll
    for (int off = 1; off < 64; off <<= 1) {
        int y = __shfl_up(x, off, 64);
        if (lane >= off) x += y;
    }
    if (lane == 63) wsum[w] = x;
    __syncthreads();
    int woff = 0;
#pragma unroll
    for (int i = 0; i < 4; i++) if (i < w) woff += wsum[i];
    __syncthreads();
    if (t < SCAN_NB) bsum[t] = woff + x - v;
}

// phase 3: add block offsets, produce cursor copy and row_ptr[N]
__global__ __launch_bounds__(256) void scan3_kernel(
    const int* __restrict__ bsum, int* __restrict__ row_ptr, int* __restrict__ cursor)
{
    const int idx = blockIdx.x * 256 + threadIdx.x;
    if (idx < N_NODES) {
        int rp = row_ptr[idx] + bsum[blockIdx.x];
        row_ptr[idx] = rp;
        cursor[idx] = rp;
    } else if (idx == N_NODES) {
        row_ptr[N_NODES] = N_EDGES;
    }
}

// scatter: only eorig (random 4B). ssrc/sdst built coalesced in fill.
__global__ __launch_bounds__(256) void scatter_kernel(
    const int* __restrict__ edge_index, int* __restrict__ cursor,
    int* __restrict__ eorig)
{
    const int e = blockIdx.x * 256 + threadIdx.x;
    if (e >= N_EDGES) return;
    const int d = edge_index[N_EDGES + e];
    const int pos = atomicAdd(&cursor[d], 1);
    eorig[pos] = e;
}

// fill: coalesced pass over sorted positions; gathers from L2-resident edge_index
__global__ __launch_bounds__(256) void fill_kernel(
    const int* __restrict__ edge_index, const int* __restrict__ eorig,
    int* __restrict__ ssrc, int* __restrict__ sdst)
{
    const int p = blockIdx.x * 256 + threadIdx.x;
    if (p >= N_EDGES) return;
    const int e = eorig[p];
    ssrc[p] = edge_index[e];
    sdst[p] = edge_index[N_EDGES + e];
}

// thread per sorted position p: all 4 head logits in registers, no shuffles.
__global__ __launch_bounds__(256) void logits_kernel(
    const int* __restrict__ ssrc, const int* __restrict__ sdst,
    const int* __restrict__ eorig, const float* __restrict__ edge_attr,
    const float* __restrict__ u, const float* __restrict__ c,
    const float* __restrict__ a_i, const float* __restrict__ a_j,
    float* __restrict__ eperm)
{
    __shared__ float uS[NH * ED_F];
    __shared__ float cS[NH];
    const int t = threadIdx.x;
    uS[t] = u[t];
    if (t < NH) cS[t] = c[t];
    __syncthreads();

    const int p = blockIdx.x * 256 + t;
    if (p >= N_EDGES) return;
    const int e = eorig[p];
    const int src = ssrc[p];
    const int dst = sdst[p];
    const float4* ap = (const float4*)(edge_attr + (size_t)e * ED_F);

    float acc[NH] = {0.f, 0.f, 0.f, 0.f};
#pragma unroll
    for (int j = 0; j < 16; j++) {
        const float4 v = ap[j];
#pragma unroll
        for (int h = 0; h < NH; h++) {
            const float4 uv = *(const float4*)&uS[h * ED_F + j * 4];
            acc[h] += v.x * uv.x + v.y * uv.y + v.z * uv.z + v.w * uv.w;
        }
    }
#pragma unroll
    for (int h = 0; h < NH; h++) {
        float a = acc[h] + a_i[h * N_NODES + dst] + a_j[h * N_NODES + src] + cS[h];
        float ev = a > 0.f ? a : 0.2f * a;
        eperm[(size_t)h * N_EDGES + p] = ev;
    }
}

// per (node, head): max + sumexp over contiguous run -> rmax, rinv.
__global__ __launch_bounds__(256) void stats_kernel(
    const int* __restrict__ row_ptr, const float* __restrict__ eperm,
    float* __restrict__ rmax, float* __restrict__ rinv)
{
    const int n = blockIdx.x * 256 + threadIdx.x;
    if (n >= N_NODES) return;
    const int b = row_ptr[n], en = row_ptr[n + 1];
    if (b >= en) return;
    const int h = blockIdx.y;
    const float* ep = eperm + (size_t)h * N_EDGES;
    float m = -INFINITY;
    for (int p = b; p < en; p++) m = fmaxf(m, ep[p]);
    float s = 0.f;
    for (int p = b; p < en; p++) s += __expf(ep[p] - m);
    rmax[h * N_NODES + n] = m;
    rinv[h * N_NODES + n] = 1.f / s;
}

// fused barrier-free aggregate: ez = edge_attr@W_edge (f16 MFMA, A-frags
// gathered directly from global in frag order) + b_edge;
// msg = alpha*(z[src]+ez+be); dst-sorted segmented reduce per wave.
// Also emits alpha in original edge order (output 1). No __syncthreads.
// Interior runs use plain stores (block-exclusive by dst contiguity);
// only boundary runs (first/last) use atomics.
__global__ __launch_bounds__(256, 1) void aggregate_mfma(
    const int* __restrict__ ssrc, const int* __restrict__ sdst,
    const int* __restrict__ eorig, const float* __restrict__ edge_attr,
    const _Float16* __restrict__ Wefrag, const float* __restrict__ b_edge,
    const _Float16* __restrict__ zb, const float* __restrict__ eperm,
    const float* __restrict__ rmax, const float* __restrict__ rinv,
    float* __restrict__ ebuf, float* __restrict__ out)
{
    __shared__ float tbuf[NH][16 * 66];      // wave-private transpose buffers (16.9KB)

    const int t = threadIdx.x;
    const int p0 = blockIdx.x * 64;
    const int lane = t & 63, h = t >> 6;
    const int q = lane >> 4, l15 = lane & 15;

    // per-lane metadata (each wave loads its own copy; L2-hot)
    const int mySrc = ssrc[p0 + lane];
    const int myDst = sdst[p0 + lane];
    const int myEor = eorig[p0 + lane];

    // alpha for own head's 64 edges; also write original-order alpha output
    const float lg = eperm[(size_t)h * N_EDGES + p0 + lane];
    const float al = __expf(lg - rmax[h * N_NODES + myDst]) * rinv[h * N_NODES + myDst];
    ebuf[(size_t)h * N_EDGES + myEor] = al;

    // A-fragments gathered directly from edge_attr in MFMA frag order:
    // lane (q,l15) holds feature chunk (kt*4+q)*8 of edge mt*16+l15.
    int esh[4];
#pragma unroll
    for (int mt = 0; mt < 4; mt++) esh[mt] = __shfl(myEor, mt * 16 + l15);

    f16x8 afr[2][4];
#pragma unroll
    for (int mt = 0; mt < 4; mt++) {
        const float* rp = edge_attr + (size_t)esh[mt] * ED_F + q * 8;
#pragma unroll
        for (int kt = 0; kt < 2; kt++) {
            const float4 v0 = *(const float4*)(rp + kt * 32);
            const float4 v1 = *(const float4*)(rp + kt * 32 + 4);
            f16x8 w;
            w[0] = (_Float16)v0.x; w[1] = (_Float16)v0.y;
            w[2] = (_Float16)v0.z; w[3] = (_Float16)v0.w;
            w[4] = (_Float16)v1.x; w[5] = (_Float16)v1.y;
            w[6] = (_Float16)v1.z; w[7] = (_Float16)v1.w;
            afr[kt][mt] = w;
        }
    }

    f16x8 wf[2][4];
#pragma unroll
    for (int kt = 0; kt < 2; kt++)
#pragma unroll
        for (int nt = 0; nt < 4; nt++)
            wf[kt][nt] = *(const f16x8*)&Wefrag[(size_t)(((h * 2 + kt) * 4 + nt) * 64 + lane) * 8];

    // zf batch A: scalar-base gathers (readlane src -> SGPR), hide under MFMA
    float zf[64];
#pragma unroll
    for (int i = 0; i < 32; i++) {
        const int s = __shfl(mySrc, i);
        zf[i] = (float)zb[((size_t)h * N_NODES + s) * OUT_F + lane];
    }

    f32x4 acc[4][4];
#pragma unroll
    for (int mt = 0; mt < 4; mt++)
#pragma unroll
        for (int nt = 0; nt < 4; nt++) acc[mt][nt] = (f32x4)0.f;

#pragma unroll
    for (int kt = 0; kt < 2; kt++)
#pragma unroll
        for (int mt = 0; mt < 4; mt++)
#pragma unroll
            for (int nt = 0; nt < 4; nt++)
                acc[mt][nt] = __builtin_amdgcn_mfma_f32_16x16x32_f16(afr[kt][mt], wf[kt][nt], acc[mt][nt], 0, 0, 0);

    // zf batch B: hides under quarters 0-1 of the reduce
#pragma unroll
    for (int i = 32; i < 64; i++) {
        const int s = __shfl(mySrc, i);
        zf[i] = (float)zb[((size_t)h * N_NODES + s) * OUT_F + lane];
    }

    const float beL = b_edge[h * OUT_F + lane];
    float* tb = tbuf[h];
    int cur = __shfl(myDst, 0);
    float accv = 0.f;
    bool first = true;

    // per-quarter transpose + segmented reduce, all wave-private (no barriers)
#pragma unroll
    for (int mt = 0; mt < 4; mt++) {
#pragma unroll
        for (int r = 0; r < 4; r++)
#pragma unroll
            for (int nt = 0; nt < 4; nt++)
                tb[(q * 4 + r) * 66 + nt * 16 + l15] = acc[mt][nt][r];

#pragma unroll
        for (int i = 0; i < 16; i++) {
            const int el = mt * 16 + i;
            const int d = __shfl(myDst, el);       // uniform -> scalar compare
            const float a = __shfl(al, el);
            const float msg = tb[i * 66 + lane];
            if (d != cur) {
                float* orow = &out[(size_t)cur * (NH * OUT_F) + h * OUT_F + lane];
                if (first) atomicAdd(orow, accv);
                else       *orow = accv;           // interior run: block-exclusive
                first = false;
                accv = 0.f;
                cur = d;
            }
            accv += a * (msg + beL + zf[el]);
        }
    }
    atomicAdd(&out[(size_t)cur * (NH * OUT_F) + h * OUT_F + lane], accv);
}

extern "C" void kernel_launch(void* const* d_in, const int* in_sizes, int n_in,
                              void* d_out, int out_size, void* d_ws, size_t ws_size,
                              hipStream_t stream) {
    const float* x         = (const float*)d_in[0];
    const int*   edge_index= (const int*)  d_in[1];
    const float* edge_attr = (const float*)d_in[2];
    const float* W_fc      = (const float*)d_in[3];
    const float* b_fc      = (const float*)d_in[4];
    const float* W_att     = (const float*)d_in[5];
    const float* b_att     = (const float*)d_in[6];
    const float* W_edge    = (const float*)d_in[7];
    const float* b_edge    = (const float*)d_in[8];
    const float* W_eatt    = (const float*)d_in[9];
    const float* b_eatt    = (const float*)d_in[10];

    float* out  = (float*)d_out;                          // (N, H*OUT)
    float* ebuf = out + (size_t)N_NODES * NH * OUT_F;     // (H, E): alpha (original order)

    // ws layout (all chunks 16B-aligned by construction)
    _Float16* zb   = (_Float16*)d_ws;                       // NH*N*64 f16 = 25.6MB
    float* a_i     = (float*)(zb + (size_t)NH * N_NODES * OUT_F);
    float* a_j     = a_i + NH * N_NODES;
    float* rmax    = a_j + NH * N_NODES;
    float* rinv    = rmax + NH * N_NODES;
    float* eperm   = rinv + NH * N_NODES;                   // (H, E) dst-sorted logits
    float* u       = eperm + (size_t)NH * N_EDGES;          // H*64
    float* c       = u + NH * 64;                           // H
    int* deg       = (int*)(c + NH);
    int* cursor    = deg + N_NODES;
    int* row_ptr   = cursor + N_NODES;                      // N+1 used, N+16 reserved
    int* eorig     = row_ptr + (N_NODES + 16);
    int* ssrc      = eorig + N_EDGES;
    int* sdst      = ssrc + N_EDGES;
    int* bsum      = sdst + N_EDGES;                        // 256 ints
    _Float16* Wfcfrag = (_Float16*)(bsum + 256);            // H*8*4*64*8 halves
    _Float16* Wefrag  = Wfcfrag + NH * 8 * 4 * 64 * 8;      // H*2*4*64*8 halves
    size_t need = (size_t)((char*)(Wefrag + NH * 2 * 4 * 64 * 8) - (char*)d_ws);

    hipMemsetAsync(out, 0, (size_t)N_NODES * NH * OUT_F * sizeof(float), stream);

    if (ws_size < need) {
        // graceful finite-absmax failure instead of OOB fault (canary)
        hipMemsetAsync(ebuf, 0, (size_t)NH * N_EDGES * sizeof(float), stream);
        return;
    }

    hipMemsetAsync(deg, 0, N_NODES * sizeof(int), stream);

    prep_kernel<<<41, 256, 0, stream>>>(W_att, b_att, W_eatt, b_eatt, W_fc, W_edge,
                                        u, c, Wfcfrag, Wefrag);

    hist_kernel<<<(N_EDGES + 255) / 256, 256, 0, stream>>>(edge_index, deg);
    scan1_kernel<<<SCAN_NB, 256, 0, stream>>>(deg, row_ptr, bsum);
    scan2_kernel<<<1, 256, 0, stream>>>(bsum);
    scan3_kernel<<<SCAN_NB, 256, 0, stream>>>(bsum, row_ptr, cursor);
    scatter_kernel<<<(N_EDGES + 255) / 256, 256, 0, stream>>>(edge_index, cursor, eorig);
    fill_kernel<<<(N_EDGES + 255) / 256, 256, 0, stream>>>(edge_index, eorig,
                                                           ssrc, sdst);

    z_gemm<<<(N_NODES + 63) / 64, 256, 0, stream>>>(x, Wfcfrag, b_fc, W_att,
                                                    zb, a_i, a_j);

    logits_kernel<<<(N_EDGES + 255) / 256, 256, 0, stream>>>(ssrc, sdst, eorig, edge_attr,
                                                             u, c, a_i, a_j, eperm);

    dim3 sg(SCAN_NB, NH);
    stats_kernel<<<sg, 256, 0, stream>>>(row_ptr, eperm, rmax, rinv);

    aggregate_mfma<<<N_EDGES / 64, 256, 0, stream>>>(ssrc, sdst, eorig, edge_attr,
                                                     Wefrag, b_edge, zb, eperm,
                                                     rmax, rinv, ebuf, out);
}

// Round 6
// 452.804 us; speedup vs baseline: 1.2005x; 1.2005x over previous
//
#include <hip/hip_runtime.h>
#include <math.h>

#define N_NODES 50000
#define N_EDGES 400000
#define IN_F 256
#define OUT_F 64
#define ED_F 64
#define NH 4
#define SCAN_NB ((N_NODES + 255) / 256)

using f16x8 = __attribute__((ext_vector_type(8))) _Float16;
using f32x4 = __attribute__((ext_vector_type(4))) float;

// block 0: u[h][f] = sum_g W_eatt[h][f][g]*We[h][g]; c[h] = b_att[h] + b_eatt[h].We[h]
// blocks 1..32: Wfcfrag (f16, MFMA b-frag order), blocks 33..40: Wefrag
// blocks 41..236: zero deg (replaces a memset dispatch)
__global__ __launch_bounds__(256) void prep_kernel(
    const float* __restrict__ W_att, const float* __restrict__ b_att,
    const float* __restrict__ W_eatt, const float* __restrict__ b_eatt,
    const float* __restrict__ W_fc, const float* __restrict__ W_edge,
    float* __restrict__ u, float* __restrict__ c,
    _Float16* __restrict__ Wfcfrag, _Float16* __restrict__ Wefrag,
    int* __restrict__ deg)
{
    const int b = blockIdx.x, t = threadIdx.x;
    if (b == 0) {
        int h = t >> 6, f = t & 63;
        const float* We = W_att + h * (2 * OUT_F + ED_F) + 2 * OUT_F;
        float s = 0.f;
        for (int g = 0; g < ED_F; g++) s += W_eatt[(h * ED_F + f) * ED_F + g] * We[g];
        u[t] = s;
        if (f == 0) {
            float cc = b_att[h];
            for (int g = 0; g < ED_F; g++) cc += b_eatt[h * ED_F + g] * We[g];
            c[h] = cc;
        }
    } else if (b <= 32) {
        // b_frag[lane][j] = B[k=quad*8+j][n=lane&15], B = W_fc[h] (256x64)
        int idx = b - 1;
        int h = idx >> 3, kt = idx & 7;
        int lane = t & 63, nt = t >> 6;
        int q = lane >> 4, l15 = lane & 15;
        f16x8 w;
#pragma unroll
        for (int j = 0; j < 8; j++) {
            int k = kt * 32 + q * 8 + j;
            int o = nt * 16 + l15;
            w[j] = (_Float16)W_fc[((size_t)h * IN_F + k) * OUT_F + o];
        }
        *(f16x8*)&Wfcfrag[(size_t)(((h * 8 + kt) * 4 + nt) * 64 + lane) * 8] = w;
    } else if (b <= 40) {
        int idx = b - 33;
        int h = idx >> 1, kt = idx & 1;
        int lane = t & 63, nt = t >> 6;
        int q = lane >> 4, l15 = lane & 15;
        f16x8 w;
#pragma unroll
        for (int j = 0; j < 8; j++) {
            int k = kt * 32 + q * 8 + j;
            int o = nt * 16 + l15;
            w[j] = (_Float16)W_edge[((size_t)h * ED_F + k) * OUT_F + o];
        }
        *(f16x8*)&Wefrag[(size_t)(((h * 2 + kt) * 4 + nt) * 64 + lane) * 8] = w;
    } else {
        const int idx = (b - 41) * 256 + t;
        if (idx < N_NODES) deg[idx] = 0;
    }
}

// z[h][n][o] = x@W_fc + b_fc, f16 MFMA 16x16x32. Block: 64 nodes, 4 waves = 4 heads.
// Fused epilogue: a_i[h][n] = z.Wi, a_j[h][n] = z.Wj (computed from fp32 acc).
__global__ __launch_bounds__(256) void z_gemm(
    const float* __restrict__ x, const _Float16* __restrict__ Wfcfrag,
    const float* __restrict__ b_fc, const float* __restrict__ W_att,
    _Float16* __restrict__ zb, float* __restrict__ a_i, float* __restrict__ a_j)
{
    __shared__ _Float16 aLDS[32 * 64 * 8];   // 32 chunks(kt,quad) x 64 nodes x 8 f16 = 32KB
    const int t = threadIdx.x;
    const int n0 = blockIdx.x * 64;
    const int lane = t & 63, h = t >> 6;
    const int q = lane >> 4, l15 = lane & 15;

    // stage x tile (64 nodes x 256 k) fp32 -> f16 frag-order LDS
    {
        const int m = t >> 2, qq = t & 3;
        const int n = n0 + m;
#pragma unroll
        for (int p = 0; p < 4; p++) {
            float4 v4[4];
            if (n < N_NODES) {
                const float4* xp = (const float4*)(x + (size_t)n * IN_F + p * 64 + qq * 16);
#pragma unroll
                for (int k = 0; k < 4; k++) v4[k] = xp[k];
            } else {
#pragma unroll
                for (int k = 0; k < 4; k++) v4[k] = make_float4(0.f, 0.f, 0.f, 0.f);
            }
            const float* vv = (const float*)v4;
#pragma unroll
            for (int i = 0; i < 2; i++) {
                int c8 = p * 8 + qq * 2 + i;
                f16x8 w;
#pragma unroll
                for (int j = 0; j < 8; j++) w[j] = (_Float16)vv[i * 8 + j];
                *(f16x8*)&aLDS[(c8 * 64 + m) * 8] = w;
            }
        }
    }
    __syncthreads();

    f32x4 acc[4][4];
#pragma unroll
    for (int mt = 0; mt < 4; mt++)
#pragma unroll
        for (int nt = 0; nt < 4; nt++) acc[mt][nt] = (f32x4)0.f;

    for (int kt = 0; kt < 8; kt++) {
        f16x8 bfr[4];
#pragma unroll
        for (int nt = 0; nt < 4; nt++)
            bfr[nt] = *(const f16x8*)&Wfcfrag[(size_t)(((h * 8 + kt) * 4 + nt) * 64 + lane) * 8];
        f16x8 afr[4];
#pragma unroll
        for (int mt = 0; mt < 4; mt++)
            afr[mt] = *(f16x8*)&aLDS[((kt * 4 + q) * 64 + mt * 16 + l15) * 8];
#pragma unroll
        for (int mt = 0; mt < 4; mt++)
#pragma unroll
            for (int nt = 0; nt < 4; nt++)
                acc[mt][nt] = __builtin_amdgcn_mfma_f32_16x16x32_f16(afr[mt], bfr[nt], acc[mt][nt], 0, 0, 0);
    }

    float bfc[4], wiv[4], wjv[4];
#pragma unroll
    for (int nt = 0; nt < 4; nt++) {
        bfc[nt] = b_fc[h * OUT_F + nt * 16 + l15];
        wiv[nt] = W_att[h * 192 + nt * 16 + l15];
        wjv[nt] = W_att[h * 192 + 64 + nt * 16 + l15];
    }

    // C/D layout: col = lane&15, row = quad*4 + reg
#pragma unroll
    for (int mt = 0; mt < 4; mt++) {
#pragma unroll
        for (int r = 0; r < 4; r++) {
            const int node = n0 + mt * 16 + q * 4 + r;
            float zv[4];
            float pi = 0.f, pj = 0.f;
#pragma unroll
            for (int nt = 0; nt < 4; nt++) {
                zv[nt] = acc[mt][nt][r] + bfc[nt];
                pi += zv[nt] * wiv[nt];
                pj += zv[nt] * wjv[nt];
            }
            // reduce over the 16 l15 lanes (same q group -> same node)
#pragma unroll
            for (int m = 8; m; m >>= 1) {
                pi += __shfl_xor(pi, m, 64);
                pj += __shfl_xor(pj, m, 64);
            }
            if (node < N_NODES) {
                _Float16* zrow = zb + ((size_t)h * N_NODES + node) * OUT_F;
#pragma unroll
                for (int nt = 0; nt < 4; nt++)
                    zrow[nt * 16 + l15] = (_Float16)zv[nt];
                if (l15 == 0) {
                    a_i[h * N_NODES + node] = pi;
                    a_j[h * N_NODES + node] = pj;
                }
            }
        }
    }
}

// --- counting-sort by dst -------------------------------------------------

__global__ __launch_bounds__(256) void hist_kernel(
    const int* __restrict__ edge_index, int* __restrict__ deg)
{
    const int e = blockIdx.x * 256 + threadIdx.x;
    if (e < N_EDGES) atomicAdd(&deg[edge_index[N_EDGES + e]], 1);
}

// hierarchical scan phase 1: per-block exclusive scan + block totals
__global__ __launch_bounds__(256) void scan1_kernel(
    const int* __restrict__ deg, int* __restrict__ row_ptr, int* __restrict__ bsum)
{
    __shared__ int wsum[4];
    const int t = threadIdx.x, lane = t & 63, w = t >> 6;
    const int idx = blockIdx.x * 256 + t;
    int v = (idx < N_NODES) ? deg[idx] : 0;
    int x = v;
#pragma unroll
    for (int off = 1; off < 64; off <<= 1) {
        int y = __shfl_up(x, off, 64);
        if (lane >= off) x += y;
    }
    if (lane == 63) wsum[w] = x;
    __syncthreads();
    int woff = 0;
#pragma unroll
    for (int i = 0; i < 4; i++) if (i < w) woff += wsum[i];
    if (idx < N_NODES) row_ptr[idx] = woff + x - v;
    if (t == 255) bsum[blockIdx.x] = woff + x;
}

// phase 2: single block scans the <=256 block totals in place (exclusive)
__global__ __launch_bounds__(256) void scan2_kernel(int* __restrict__ bsum)
{
    __shared__ int wsum[4];
    const int t = threadIdx.x, lane = t & 63, w = t >> 6;
    int v = (t < SCAN_NB) ? bsum[t] : 0;
    int x = v;
#pragma unroll
    for (int off = 1; off < 64; off <<= 1) {
        int y = __shfl_up(x, off, 64);
        if (lane >= off) x += y;
    }
    if (lane == 63) wsum[w] = x;
    __syncthreads();
    int woff = 0;
#pragma unroll
    for (int i = 0; i < 4; i++) if (i < w) woff += wsum[i];
    __syncthreads();
    if (t < SCAN_NB) bsum[t] = woff + x - v;
}

// phase 3: add block offsets, produce cursor copy and row_ptr[N]
__global__ __launch_bounds__(256) void scan3_kernel(
    const int* __restrict__ bsum, int* __restrict__ row_ptr, int* __restrict__ cursor)
{
    const int idx = blockIdx.x * 256 + threadIdx.x;
    if (idx < N_NODES) {
        int rp = row_ptr[idx] + bsum[blockIdx.x];
        row_ptr[idx] = rp;
        cursor[idx] = rp;
    } else if (idx == N_NODES) {
        row_ptr[N_NODES] = N_EDGES;
    }
}

// scatter: writes eorig + ssrc + sdst at sorted position (fill merged back)
__global__ __launch_bounds__(256) void scatter_kernel(
    const int* __restrict__ edge_index, int* __restrict__ cursor,
    int* __restrict__ eorig, int* __restrict__ ssrc, int* __restrict__ sdst)
{
    const int e = blockIdx.x * 256 + threadIdx.x;
    if (e >= N_EDGES) return;
    const int s = edge_index[e];
    const int d = edge_index[N_EDGES + e];
    const int pos = atomicAdd(&cursor[d], 1);
    eorig[pos] = e;
    ssrc[pos] = s;
    sdst[pos] = d;
}

// thread per sorted position p: all 4 head logits in registers, no shuffles.
__global__ __launch_bounds__(256) void logits_kernel(
    const int* __restrict__ ssrc, const int* __restrict__ sdst,
    const int* __restrict__ eorig, const float* __restrict__ edge_attr,
    const float* __restrict__ u, const float* __restrict__ c,
    const float* __restrict__ a_i, const float* __restrict__ a_j,
    float* __restrict__ eperm)
{
    __shared__ float uS[NH * ED_F];
    __shared__ float cS[NH];
    const int t = threadIdx.x;
    uS[t] = u[t];
    if (t < NH) cS[t] = c[t];
    __syncthreads();

    const int p = blockIdx.x * 256 + t;
    if (p >= N_EDGES) return;
    const int e = eorig[p];
    const int src = ssrc[p];
    const int dst = sdst[p];
    const float4* ap = (const float4*)(edge_attr + (size_t)e * ED_F);

    float acc[NH] = {0.f, 0.f, 0.f, 0.f};
#pragma unroll
    for (int j = 0; j < 16; j++) {
        const float4 v = ap[j];
#pragma unroll
        for (int h = 0; h < NH; h++) {
            const float4 uv = *(const float4*)&uS[h * ED_F + j * 4];
            acc[h] += v.x * uv.x + v.y * uv.y + v.z * uv.z + v.w * uv.w;
        }
    }
#pragma unroll
    for (int h = 0; h < NH; h++) {
        float a = acc[h] + a_i[h * N_NODES + dst] + a_j[h * N_NODES + src] + cS[h];
        float ev = a > 0.f ? a : 0.2f * a;
        eperm[(size_t)h * N_EDGES + p] = ev;
    }
}

// per (node, head): serial softmax over the node's contiguous sorted run.
// Converts eperm logits -> alpha in place; scatters alpha to original order.
__global__ __launch_bounds__(256) void softmax_kernel(
    const int* __restrict__ row_ptr, const int* __restrict__ eorig,
    float* __restrict__ eperm, float* __restrict__ alpha_out)
{
    const int n = blockIdx.x * 256 + threadIdx.x;
    if (n >= N_NODES) return;
    const int b = row_ptr[n], en = row_ptr[n + 1];
    if (b >= en) return;
    const int h = blockIdx.y;
    float* ep = eperm + (size_t)h * N_EDGES;
    float* ao = alpha_out + (size_t)h * N_EDGES;
    float m = -INFINITY;
    for (int p = b; p < en; p++) m = fmaxf(m, ep[p]);
    float s = 0.f;
    for (int p = b; p < en; p++) { float v = __expf(ep[p] - m); ep[p] = v; s += v; }
    const float inv = 1.f / s;
    for (int p = b; p < en; p++) {
        float a = ep[p] * inv;
        ep[p] = a;
        ao[eorig[p]] = a;
    }
}

// fused: ez = edge_attr@W_edge (f16 MFMA) + b_edge; msg = alpha*(z[src]+ez+be);
// dst-sorted segmented reduction. Transpose per mt-quarter in a WAVE-PRIVATE
// LDS region -> only 2 barriers. alpha precomputed (softmax). zf gathers
// pipelined one quarter ahead.
__global__ __launch_bounds__(256) void aggregate_mfma(
    const int* __restrict__ ssrc, const int* __restrict__ sdst,
    const int* __restrict__ eorig, const float* __restrict__ edge_attr,
    const _Float16* __restrict__ Wefrag, const float* __restrict__ b_edge,
    const _Float16* __restrict__ zb, const float* __restrict__ eperm,
    float* __restrict__ out)
{
    __shared__ float tbuf[NH * 16 * 66];     // 16896B; front 8KB doubles as f16 A-stage
    __shared__ int srcS[64], dstS[64];
    __shared__ float alphaS[NH][64];
    _Float16* aLDS = (_Float16*)tbuf;        // 8 chunks x 64 edges x 8 f16 = 8KB

    const int t = threadIdx.x;
    const int p0 = blockIdx.x * 64;
    const int lane = t & 63, h = t >> 6;
    const int q = lane >> 4, l15 = lane & 15;

    if (t < 64) srcS[t] = ssrc[p0 + t];
    else if (t < 128) dstS[t - 64] = sdst[p0 + t - 64];

    // alpha (already normalized by softmax); wave-private row of alphaS
    alphaS[h][lane] = eperm[(size_t)h * N_EDGES + p0 + lane];

    // stage edge_attr rows (gathered via eorig) fp32 -> f16 frag-order LDS
    {
        const int m = t >> 2, qq = t & 3;
        const int er = eorig[p0 + m];
        const float4* ap = (const float4*)(edge_attr + (size_t)er * ED_F + qq * 16);
        float4 v4[4];
#pragma unroll
        for (int k = 0; k < 4; k++) v4[k] = ap[k];
        const float* vv = (const float*)v4;
#pragma unroll
        for (int i = 0; i < 2; i++) {
            int c8 = qq * 2 + i;
            f16x8 w;
#pragma unroll
            for (int j = 0; j < 8; j++) w[j] = (_Float16)vv[i * 8 + j];
            *(f16x8*)&aLDS[(c8 * 64 + m) * 8] = w;
        }
    }
    __syncthreads();

    // zf quarter-0 prefetch issued early: hides under Wefrag loads + MFMA
    float zf[2][16];
#pragma unroll
    for (int i = 0; i < 16; i++)
        zf[0][i] = (float)zb[((size_t)h * N_NODES + srcS[i]) * OUT_F + lane];

    f16x8 wf[2][4];
#pragma unroll
    for (int kt = 0; kt < 2; kt++)
#pragma unroll
        for (int nt = 0; nt < 4; nt++)
            wf[kt][nt] = *(const f16x8*)&Wefrag[(size_t)(((h * 2 + kt) * 4 + nt) * 64 + lane) * 8];

    f32x4 acc[4][4];
#pragma unroll
    for (int mt = 0; mt < 4; mt++)
#pragma unroll
        for (int nt = 0; nt < 4; nt++) acc[mt][nt] = (f32x4)0.f;

#pragma unroll
    for (int kt = 0; kt < 2; kt++) {
        f16x8 afr[4];
#pragma unroll
        for (int mt = 0; mt < 4; mt++)
            afr[mt] = *(f16x8*)&aLDS[((kt * 4 + q) * 64 + mt * 16 + l15) * 8];
#pragma unroll
        for (int mt = 0; mt < 4; mt++)
#pragma unroll
            for (int nt = 0; nt < 4; nt++)
                acc[mt][nt] = __builtin_amdgcn_mfma_f32_16x16x32_f16(afr[mt], wf[kt][nt], acc[mt][nt], 0, 0, 0);
    }

    __syncthreads();   // all waves done reading aLDS before tbuf overwrites it

    const float beL = b_edge[h * OUT_F + lane];
    float* tb = &tbuf[h * 16 * 66];
    int cur = dstS[0];
    float accv = 0.f;

    // per-quarter: prefetch next zf, transpose, segmented reduce (wave-private)
#pragma unroll
    for (int mt = 0; mt < 4; mt++) {
        if (mt < 3) {
#pragma unroll
            for (int i = 0; i < 16; i++)
                zf[(mt + 1) & 1][i] =
                    (float)zb[((size_t)h * N_NODES + srcS[(mt + 1) * 16 + i]) * OUT_F + lane];
        }
#pragma unroll
        for (int r = 0; r < 4; r++)
#pragma unroll
            for (int nt = 0; nt < 4; nt++)
                tb[(q * 4 + r) * 66 + nt * 16 + l15] = acc[mt][nt][r];

#pragma unroll
        for (int i = 0; i < 16; i++) {
            const int el = mt * 16 + i;
            const int d = dstS[el];
            const float msg = tb[i * 66 + lane];
            if (d != cur) {
                atomicAdd(&out[(size_t)cur * (NH * OUT_F) + h * OUT_F + lane], accv);
                accv = 0.f;
                cur = d;
            }
            accv += alphaS[h][el] * (msg + beL + zf[mt & 1][i]);
        }
    }
    atomicAdd(&out[(size_t)cur * (NH * OUT_F) + h * OUT_F + lane], accv);
}

extern "C" void kernel_launch(void* const* d_in, const int* in_sizes, int n_in,
                              void* d_out, int out_size, void* d_ws, size_t ws_size,
                              hipStream_t stream) {
    const float* x         = (const float*)d_in[0];
    const int*   edge_index= (const int*)  d_in[1];
    const float* edge_attr = (const float*)d_in[2];
    const float* W_fc      = (const float*)d_in[3];
    const float* b_fc      = (const float*)d_in[4];
    const float* W_att     = (const float*)d_in[5];
    const float* b_att     = (const float*)d_in[6];
    const float* W_edge    = (const float*)d_in[7];
    const float* b_edge    = (const float*)d_in[8];
    const float* W_eatt    = (const float*)d_in[9];
    const float* b_eatt    = (const float*)d_in[10];

    float* out  = (float*)d_out;                          // (N, H*OUT)
    float* ebuf = out + (size_t)N_NODES * NH * OUT_F;     // (H, E): alpha (original order)

    // ws layout (all chunks 16B-aligned by construction)
    _Float16* zb   = (_Float16*)d_ws;                       // NH*N*64 f16 = 25.6MB
    float* a_i     = (float*)(zb + (size_t)NH * N_NODES * OUT_F);
    float* a_j     = a_i + NH * N_NODES;
    float* eperm   = a_j + NH * N_NODES;                    // (H, E) dst-sorted logits->alpha
    float* u       = eperm + (size_t)NH * N_EDGES;          // H*64
    float* c       = u + NH * 64;                           // H
    int* deg       = (int*)(c + NH);
    int* cursor    = deg + N_NODES;
    int* row_ptr   = cursor + N_NODES;                      // N+1 used, N+16 reserved
    int* eorig     = row_ptr + (N_NODES + 16);
    int* ssrc      = eorig + N_EDGES;
    int* sdst      = ssrc + N_EDGES;
    int* bsum      = sdst + N_EDGES;                        // 256 ints
    _Float16* Wfcfrag = (_Float16*)(bsum + 256);            // H*8*4*64*8 halves
    _Float16* Wefrag  = Wfcfrag + NH * 8 * 4 * 64 * 8;      // H*2*4*64*8 halves
    size_t need = (size_t)((char*)(Wefrag + NH * 2 * 4 * 64 * 8) - (char*)d_ws);

    hipMemsetAsync(out, 0, (size_t)N_NODES * NH * OUT_F * sizeof(float), stream);

    if (ws_size < need) {
        // graceful finite-absmax failure instead of OOB fault (canary)
        hipMemsetAsync(ebuf, 0, (size_t)NH * N_EDGES * sizeof(float), stream);
        return;
    }

    prep_kernel<<<41 + SCAN_NB, 256, 0, stream>>>(W_att, b_att, W_eatt, b_eatt,
                                                  W_fc, W_edge, u, c,
                                                  Wfcfrag, Wefrag, deg);

    hist_kernel<<<(N_EDGES + 255) / 256, 256, 0, stream>>>(edge_index, deg);
    scan1_kernel<<<SCAN_NB, 256, 0, stream>>>(deg, row_ptr, bsum);
    scan2_kernel<<<1, 256, 0, stream>>>(bsum);
    scan3_kernel<<<SCAN_NB, 256, 0, stream>>>(bsum, row_ptr, cursor);
    scatter_kernel<<<(N_EDGES + 255) / 256, 256, 0, stream>>>(edge_index, cursor,
                                                              eorig, ssrc, sdst);

    z_gemm<<<(N_NODES + 63) / 64, 256, 0, stream>>>(x, Wfcfrag, b_fc, W_att,
                                                    zb, a_i, a_j);

    logits_kernel<<<(N_EDGES + 255) / 256, 256, 0, stream>>>(ssrc, sdst, eorig, edge_attr,
                                                             u, c, a_i, a_j, eperm);

    dim3 sg(SCAN_NB, NH);
    softmax_kernel<<<sg, 256, 0, stream>>>(row_ptr, eorig, eperm, ebuf);

    aggregate_mfma<<<N_EDGES / 64, 256, 0, stream>>>(ssrc, sdst, eorig, edge_attr,
                                                     Wefrag, b_edge, zb, eperm, out);
}

// Round 7
// 430.139 us; speedup vs baseline: 1.2638x; 1.0527x over previous
//
#include <hip/hip_runtime.h>
#include <math.h>

#define N_NODES 50000
#define N_EDGES 400000
#define IN_F 256
#define OUT_F 64
#define ED_F 64
#define NH 4
#define SCAN_NB ((N_NODES + 255) / 256)

using f16x8 = __attribute__((ext_vector_type(8))) _Float16;
using f32x4 = __attribute__((ext_vector_type(4))) float;

// block 0: u[h][f] = sum_g W_eatt[h][f][g]*We[h][g]; c[h] = b_att[h] + b_eatt[h].We[h]
// blocks 1..32: Wfcfrag (f16, MFMA b-frag order), blocks 33..40: Wefrag
// blocks 41..236: zero deg (replaces a memset dispatch)
__global__ __launch_bounds__(256) void prep_kernel(
    const float* __restrict__ W_att, const float* __restrict__ b_att,
    const float* __restrict__ W_eatt, const float* __restrict__ b_eatt,
    const float* __restrict__ W_fc, const float* __restrict__ W_edge,
    float* __restrict__ u, float* __restrict__ c,
    _Float16* __restrict__ Wfcfrag, _Float16* __restrict__ Wefrag,
    int* __restrict__ deg)
{
    const int b = blockIdx.x, t = threadIdx.x;
    if (b == 0) {
        int h = t >> 6, f = t & 63;
        const float* We = W_att + h * (2 * OUT_F + ED_F) + 2 * OUT_F;
        float s = 0.f;
        for (int g = 0; g < ED_F; g++) s += W_eatt[(h * ED_F + f) * ED_F + g] * We[g];
        u[t] = s;
        if (f == 0) {
            float cc = b_att[h];
            for (int g = 0; g < ED_F; g++) cc += b_eatt[h * ED_F + g] * We[g];
            c[h] = cc;
        }
    } else if (b <= 32) {
        // b_frag[lane][j] = B[k=quad*8+j][n=lane&15], B = W_fc[h] (256x64)
        int idx = b - 1;
        int h = idx >> 3, kt = idx & 7;
        int lane = t & 63, nt = t >> 6;
        int q = lane >> 4, l15 = lane & 15;
        f16x8 w;
#pragma unroll
        for (int j = 0; j < 8; j++) {
            int k = kt * 32 + q * 8 + j;
            int o = nt * 16 + l15;
            w[j] = (_Float16)W_fc[((size_t)h * IN_F + k) * OUT_F + o];
        }
        *(f16x8*)&Wfcfrag[(size_t)(((h * 8 + kt) * 4 + nt) * 64 + lane) * 8] = w;
    } else if (b <= 40) {
        int idx = b - 33;
        int h = idx >> 1, kt = idx & 1;
        int lane = t & 63, nt = t >> 6;
        int q = lane >> 4, l15 = lane & 15;
        f16x8 w;
#pragma unroll
        for (int j = 0; j < 8; j++) {
            int k = kt * 32 + q * 8 + j;
            int o = nt * 16 + l15;
            w[j] = (_Float16)W_edge[((size_t)h * ED_F + k) * OUT_F + o];
        }
        *(f16x8*)&Wefrag[(size_t)(((h * 2 + kt) * 4 + nt) * 64 + lane) * 8] = w;
    } else {
        const int idx = (b - 41) * 256 + t;
        if (idx < N_NODES) deg[idx] = 0;
    }
}

// z[h][n][o] = x@W_fc + b_fc, f16 MFMA 16x16x32. Block: 64 nodes, 4 waves = 4 heads.
// Fused epilogue: a_i[h][n] = z.Wi, a_j[h][n] = z.Wj (computed from fp32 acc).
__global__ __launch_bounds__(256) void z_gemm(
    const float* __restrict__ x, const _Float16* __restrict__ Wfcfrag,
    const float* __restrict__ b_fc, const float* __restrict__ W_att,
    _Float16* __restrict__ zb, float* __restrict__ a_i, float* __restrict__ a_j)
{
    __shared__ _Float16 aLDS[32 * 64 * 8];   // 32 chunks(kt,quad) x 64 nodes x 8 f16 = 32KB
    const int t = threadIdx.x;
    const int n0 = blockIdx.x * 64;
    const int lane = t & 63, h = t >> 6;
    const int q = lane >> 4, l15 = lane & 15;

    // stage x tile (64 nodes x 256 k) fp32 -> f16 frag-order LDS
    {
        const int m = t >> 2, qq = t & 3;
        const int n = n0 + m;
#pragma unroll
        for (int p = 0; p < 4; p++) {
            float4 v4[4];
            if (n < N_NODES) {
                const float4* xp = (const float4*)(x + (size_t)n * IN_F + p * 64 + qq * 16);
#pragma unroll
                for (int k = 0; k < 4; k++) v4[k] = xp[k];
            } else {
#pragma unroll
                for (int k = 0; k < 4; k++) v4[k] = make_float4(0.f, 0.f, 0.f, 0.f);
            }
            const float* vv = (const float*)v4;
#pragma unroll
            for (int i = 0; i < 2; i++) {
                int c8 = p * 8 + qq * 2 + i;
                f16x8 w;
#pragma unroll
                for (int j = 0; j < 8; j++) w[j] = (_Float16)vv[i * 8 + j];
                *(f16x8*)&aLDS[(c8 * 64 + m) * 8] = w;
            }
        }
    }
    __syncthreads();

    f32x4 acc[4][4];
#pragma unroll
    for (int mt = 0; mt < 4; mt++)
#pragma unroll
        for (int nt = 0; nt < 4; nt++) acc[mt][nt] = (f32x4)0.f;

    for (int kt = 0; kt < 8; kt++) {
        f16x8 bfr[4];
#pragma unroll
        for (int nt = 0; nt < 4; nt++)
            bfr[nt] = *(const f16x8*)&Wfcfrag[(size_t)(((h * 8 + kt) * 4 + nt) * 64 + lane) * 8];
        f16x8 afr[4];
#pragma unroll
        for (int mt = 0; mt < 4; mt++)
            afr[mt] = *(f16x8*)&aLDS[((kt * 4 + q) * 64 + mt * 16 + l15) * 8];
#pragma unroll
        for (int mt = 0; mt < 4; mt++)
#pragma unroll
            for (int nt = 0; nt < 4; nt++)
                acc[mt][nt] = __builtin_amdgcn_mfma_f32_16x16x32_f16(afr[mt], bfr[nt], acc[mt][nt], 0, 0, 0);
    }

    float bfc[4], wiv[4], wjv[4];
#pragma unroll
    for (int nt = 0; nt < 4; nt++) {
        bfc[nt] = b_fc[h * OUT_F + nt * 16 + l15];
        wiv[nt] = W_att[h * 192 + nt * 16 + l15];
        wjv[nt] = W_att[h * 192 + 64 + nt * 16 + l15];
    }

    // C/D layout: col = lane&15, row = quad*4 + reg
#pragma unroll
    for (int mt = 0; mt < 4; mt++) {
#pragma unroll
        for (int r = 0; r < 4; r++) {
            const int node = n0 + mt * 16 + q * 4 + r;
            float zv[4];
            float pi = 0.f, pj = 0.f;
#pragma unroll
            for (int nt = 0; nt < 4; nt++) {
                zv[nt] = acc[mt][nt][r] + bfc[nt];
                pi += zv[nt] * wiv[nt];
                pj += zv[nt] * wjv[nt];
            }
            // reduce over the 16 l15 lanes (same q group -> same node)
#pragma unroll
            for (int m = 8; m; m >>= 1) {
                pi += __shfl_xor(pi, m, 64);
                pj += __shfl_xor(pj, m, 64);
            }
            if (node < N_NODES) {
                _Float16* zrow = zb + ((size_t)h * N_NODES + node) * OUT_F;
#pragma unroll
                for (int nt = 0; nt < 4; nt++)
                    zrow[nt * 16 + l15] = (_Float16)zv[nt];
                if (l15 == 0) {
                    a_i[h * N_NODES + node] = pi;
                    a_j[h * N_NODES + node] = pj;
                }
            }
        }
    }
}

// --- counting-sort by dst -------------------------------------------------

__global__ __launch_bounds__(256) void hist_kernel(
    const int* __restrict__ edge_index, int* __restrict__ deg)
{
    const int e = blockIdx.x * 256 + threadIdx.x;
    if (e < N_EDGES) atomicAdd(&deg[edge_index[N_EDGES + e]], 1);
}

// hierarchical scan phase 1: per-block exclusive scan + block totals
__global__ __launch_bounds__(256) void scan1_kernel(
    const int* __restrict__ deg, int* __restrict__ row_ptr, int* __restrict__ bsum)
{
    __shared__ int wsum[4];
    const int t = threadIdx.x, lane = t & 63, w = t >> 6;
    const int idx = blockIdx.x * 256 + t;
    int v = (idx < N_NODES) ? deg[idx] : 0;
    int x = v;
#pragma unroll
    for (int off = 1; off < 64; off <<= 1) {
        int y = __shfl_up(x, off, 64);
        if (lane >= off) x += y;
    }
    if (lane == 63) wsum[w] = x;
    __syncthreads();
    int woff = 0;
#pragma unroll
    for (int i = 0; i < 4; i++) if (i < w) woff += wsum[i];
    if (idx < N_NODES) row_ptr[idx] = woff + x - v;
    if (t == 255) bsum[blockIdx.x] = woff + x;
}

// phase 2: single block scans the <=256 block totals in place (exclusive)
__global__ __launch_bounds__(256) void scan2_kernel(int* __restrict__ bsum)
{
    __shared__ int wsum[4];
    const int t = threadIdx.x, lane = t & 63, w = t >> 6;
    int v = (t < SCAN_NB) ? bsum[t] : 0;
    int x = v;
#pragma unroll
    for (int off = 1; off < 64; off <<= 1) {
        int y = __shfl_up(x, off, 64);
        if (lane >= off) x += y;
    }
    if (lane == 63) wsum[w] = x;
    __syncthreads();
    int woff = 0;
#pragma unroll
    for (int i = 0; i < 4; i++) if (i < w) woff += wsum[i];
    __syncthreads();
    if (t < SCAN_NB) bsum[t] = woff + x - v;
}

// phase 3: add block offsets, produce cursor copy and row_ptr[N]
__global__ __launch_bounds__(256) void scan3_kernel(
    const int* __restrict__ bsum, int* __restrict__ row_ptr, int* __restrict__ cursor)
{
    const int idx = blockIdx.x * 256 + threadIdx.x;
    if (idx < N_NODES) {
        int rp = row_ptr[idx] + bsum[blockIdx.x];
        row_ptr[idx] = rp;
        cursor[idx] = rp;
    } else if (idx == N_NODES) {
        row_ptr[N_NODES] = N_EDGES;
    }
}

// scatter: eorig (random 4B) + epos (coalesced). ssrc/sdst built in fill (gather).
__global__ __launch_bounds__(256) void scatter_kernel(
    const int* __restrict__ edge_index, int* __restrict__ cursor,
    int* __restrict__ eorig, int* __restrict__ epos)
{
    const int e = blockIdx.x * 256 + threadIdx.x;
    if (e >= N_EDGES) return;
    const int d = edge_index[N_EDGES + e];
    const int pos = atomicAdd(&cursor[d], 1);
    eorig[pos] = e;
    epos[e] = pos;
}

// fill: coalesced pass over sorted positions; gathers from L2-resident edge_index
__global__ __launch_bounds__(256) void fill_kernel(
    const int* __restrict__ edge_index, const int* __restrict__ eorig,
    int* __restrict__ ssrc, int* __restrict__ sdst)
{
    const int p = blockIdx.x * 256 + threadIdx.x;
    if (p >= N_EDGES) return;
    const int e = eorig[p];
    ssrc[p] = edge_index[e];
    sdst[p] = edge_index[N_EDGES + e];
}

// thread per sorted position p: all 4 head logits in registers, one float4 store.
__global__ __launch_bounds__(256) void logits_kernel(
    const int* __restrict__ ssrc, const int* __restrict__ sdst,
    const int* __restrict__ eorig, const float* __restrict__ edge_attr,
    const float* __restrict__ u, const float* __restrict__ c,
    const float* __restrict__ a_i, const float* __restrict__ a_j,
    float4* __restrict__ epermT)
{
    __shared__ float uS[NH * ED_F];
    __shared__ float cS[NH];
    const int t = threadIdx.x;
    uS[t] = u[t];
    if (t < NH) cS[t] = c[t];
    __syncthreads();

    const int p = blockIdx.x * 256 + t;
    if (p >= N_EDGES) return;
    const int e = eorig[p];
    const int src = ssrc[p];
    const int dst = sdst[p];
    const float4* ap = (const float4*)(edge_attr + (size_t)e * ED_F);

    float acc[NH] = {0.f, 0.f, 0.f, 0.f};
#pragma unroll
    for (int j = 0; j < 16; j++) {
        const float4 v = ap[j];
#pragma unroll
        for (int h = 0; h < NH; h++) {
            const float4 uv = *(const float4*)&uS[h * ED_F + j * 4];
            acc[h] += v.x * uv.x + v.y * uv.y + v.z * uv.z + v.w * uv.w;
        }
    }
    float4 ev;
    float* evp = (float*)&ev;
#pragma unroll
    for (int h = 0; h < NH; h++) {
        float a = acc[h] + a_i[h * N_NODES + dst] + a_j[h * N_NODES + src] + cS[h];
        evp[h] = a > 0.f ? a : 0.2f * a;
    }
    epermT[p] = ev;
}

// per node: softmax over contiguous run, ALL 4 heads at once (float4).
// In-place logits -> alpha. No scatter (original-order output via gather kernel).
__global__ __launch_bounds__(256) void softmax_kernel(
    const int* __restrict__ row_ptr, float4* __restrict__ epermT)
{
    const int n = blockIdx.x * 256 + threadIdx.x;
    if (n >= N_NODES) return;
    const int b = row_ptr[n], en = row_ptr[n + 1];
    if (b >= en) return;

    float4 m4 = make_float4(-INFINITY, -INFINITY, -INFINITY, -INFINITY);
    for (int p = b; p < en; p++) {
        const float4 v = epermT[p];
        m4.x = fmaxf(m4.x, v.x); m4.y = fmaxf(m4.y, v.y);
        m4.z = fmaxf(m4.z, v.z); m4.w = fmaxf(m4.w, v.w);
    }
    float4 s4 = make_float4(0.f, 0.f, 0.f, 0.f);
    for (int p = b; p < en; p++) {
        const float4 v = epermT[p];
        s4.x += __expf(v.x - m4.x); s4.y += __expf(v.y - m4.y);
        s4.z += __expf(v.z - m4.z); s4.w += __expf(v.w - m4.w);
    }
    const float4 i4 = make_float4(1.f / s4.x, 1.f / s4.y, 1.f / s4.z, 1.f / s4.w);
    for (int p = b; p < en; p++) {
        const float4 v = epermT[p];
        epermT[p] = make_float4(__expf(v.x - m4.x) * i4.x, __expf(v.y - m4.y) * i4.y,
                                __expf(v.z - m4.z) * i4.z, __expf(v.w - m4.w) * i4.w);
    }
}

// alpha in ORIGINAL edge order: coalesced epos read + plane writes; random
// float4 gathers absorbed by L2/L3.
__global__ __launch_bounds__(256) void alpha_orig_kernel(
    const int* __restrict__ epos, const float4* __restrict__ epermT,
    float* __restrict__ ebuf)
{
    const int e = blockIdx.x * 256 + threadIdx.x;
    if (e >= N_EDGES) return;
    const float4 a = epermT[epos[e]];
    ebuf[e] = a.x;
    ebuf[(size_t)N_EDGES + e] = a.y;
    ebuf[(size_t)2 * N_EDGES + e] = a.z;
    ebuf[(size_t)3 * N_EDGES + e] = a.w;
}

// fused: ez = edge_attr@W_edge (f16 MFMA) + b_edge; msg = alpha*(z[src]+ez+be);
// dst-sorted segmented reduction. Transpose per mt-quarter in a WAVE-PRIVATE
// LDS region -> only 2 barriers. alpha read as float4 from epermT.
__global__ __launch_bounds__(256) void aggregate_mfma(
    const int* __restrict__ ssrc, const int* __restrict__ sdst,
    const int* __restrict__ eorig, const float* __restrict__ edge_attr,
    const _Float16* __restrict__ Wefrag, const float* __restrict__ b_edge,
    const _Float16* __restrict__ zb, const float4* __restrict__ epermT,
    float* __restrict__ out)
{
    __shared__ float tbuf[NH * 16 * 66];     // 16896B; front 8KB doubles as f16 A-stage
    __shared__ int srcS[64], dstS[64];
    __shared__ float alphaS[NH][64];
    _Float16* aLDS = (_Float16*)tbuf;        // 8 chunks x 64 edges x 8 f16 = 8KB

    const int t = threadIdx.x;
    const int p0 = blockIdx.x * 64;
    const int lane = t & 63, h = t >> 6;
    const int q = lane >> 4, l15 = lane & 15;

    if (t < 64) srcS[t] = ssrc[p0 + t];
    else if (t < 128) dstS[t - 64] = sdst[p0 + t - 64];

    // alpha: each wave loads the block's 64 float4s (L1-hot across waves),
    // keeps its own head component. Wave-private alphaS row -> no barrier.
    {
        const float4 a4 = epermT[p0 + lane];
        alphaS[h][lane] = ((const float*)&a4)[h];
    }

    // stage edge_attr rows (gathered via eorig) fp32 -> f16 frag-order LDS
    {
        const int m = t >> 2, qq = t & 3;
        const int er = eorig[p0 + m];
        const float4* ap = (const float4*)(edge_attr + (size_t)er * ED_F + qq * 16);
        float4 v4[4];
#pragma unroll
        for (int k = 0; k < 4; k++) v4[k] = ap[k];
        const float* vv = (const float*)v4;
#pragma unroll
        for (int i = 0; i < 2; i++) {
            int c8 = qq * 2 + i;
            f16x8 w;
#pragma unroll
            for (int j = 0; j < 8; j++) w[j] = (_Float16)vv[i * 8 + j];
            *(f16x8*)&aLDS[(c8 * 64 + m) * 8] = w;
        }
    }
    __syncthreads();

    f16x8 wf[2][4];
#pragma unroll
    for (int kt = 0; kt < 2; kt++)
#pragma unroll
        for (int nt = 0; nt < 4; nt++)
            wf[kt][nt] = *(const f16x8*)&Wefrag[(size_t)(((h * 2 + kt) * 4 + nt) * 64 + lane) * 8];

    f32x4 acc[4][4];
#pragma unroll
    for (int mt = 0; mt < 4; mt++)
#pragma unroll
        for (int nt = 0; nt < 4; nt++) acc[mt][nt] = (f32x4)0.f;

#pragma unroll
    for (int kt = 0; kt < 2; kt++) {
        f16x8 afr[4];
#pragma unroll
        for (int mt = 0; mt < 4; mt++)
            afr[mt] = *(f16x8*)&aLDS[((kt * 4 + q) * 64 + mt * 16 + l15) * 8];
#pragma unroll
        for (int mt = 0; mt < 4; mt++)
#pragma unroll
            for (int nt = 0; nt < 4; nt++)
                acc[mt][nt] = __builtin_amdgcn_mfma_f32_16x16x32_f16(afr[mt], wf[kt][nt], acc[mt][nt], 0, 0, 0);
    }

    __syncthreads();   // all waves done reading aLDS before tbuf overwrites it

    const float beL = b_edge[h * OUT_F + lane];
    float* tb = &tbuf[h * 16 * 66];
    int cur = dstS[0];
    float accv = 0.f;

    // per-quarter transpose + zf prefetch + segmented reduce (wave-private)
#pragma unroll
    for (int mt = 0; mt < 4; mt++) {
#pragma unroll
        for (int r = 0; r < 4; r++)
#pragma unroll
            for (int nt = 0; nt < 4; nt++)
                tb[(q * 4 + r) * 66 + nt * 16 + l15] = acc[mt][nt][r];

        // prefetch the 16 z[src] gathers for this quarter (static unroll -> regs)
        float zf[16];
#pragma unroll
        for (int i = 0; i < 16; i++)
            zf[i] = (float)zb[((size_t)h * N_NODES + srcS[mt * 16 + i]) * OUT_F + lane];

#pragma unroll
        for (int i = 0; i < 16; i++) {
            const int el = mt * 16 + i;
            const int d = dstS[el];
            const float msg = tb[i * 66 + lane];
            if (d != cur) {
                atomicAdd(&out[(size_t)cur * (NH * OUT_F) + h * OUT_F + lane], accv);
                accv = 0.f;
                cur = d;
            }
            accv += alphaS[h][el] * (msg + beL + zf[i]);
        }
    }
    atomicAdd(&out[(size_t)cur * (NH * OUT_F) + h * OUT_F + lane], accv);
}

extern "C" void kernel_launch(void* const* d_in, const int* in_sizes, int n_in,
                              void* d_out, int out_size, void* d_ws, size_t ws_size,
                              hipStream_t stream) {
    const float* x         = (const float*)d_in[0];
    const int*   edge_index= (const int*)  d_in[1];
    const float* edge_attr = (const float*)d_in[2];
    const float* W_fc      = (const float*)d_in[3];
    const float* b_fc      = (const float*)d_in[4];
    const float* W_att     = (const float*)d_in[5];
    const float* b_att     = (const float*)d_in[6];
    const float* W_edge    = (const float*)d_in[7];
    const float* b_edge    = (const float*)d_in[8];
    const float* W_eatt    = (const float*)d_in[9];
    const float* b_eatt    = (const float*)d_in[10];

    float* out  = (float*)d_out;                          // (N, H*OUT)
    float* ebuf = out + (size_t)N_NODES * NH * OUT_F;     // (H, E): alpha (original order)

    // ws layout (epermT first after zb to keep 16B alignment)
    _Float16* zb   = (_Float16*)d_ws;                       // NH*N*64 f16 = 25.6MB
    float4* epermT = (float4*)(zb + (size_t)NH * N_NODES * OUT_F);  // E float4 = 6.4MB
    float* a_i     = (float*)(epermT + N_EDGES);
    float* a_j     = a_i + NH * N_NODES;
    float* u       = a_j + NH * N_NODES;                    // H*64
    float* c       = u + NH * 64;                           // H
    int* deg       = (int*)(c + NH);
    int* cursor    = deg + N_NODES;
    int* row_ptr   = cursor + N_NODES;                      // N+1 used, N+16 reserved
    int* epos      = row_ptr + (N_NODES + 16);
    int* eorig     = epos + N_EDGES;
    int* ssrc      = eorig + N_EDGES;
    int* sdst      = ssrc + N_EDGES;
    int* bsum      = sdst + N_EDGES;                        // 256 ints
    _Float16* Wfcfrag = (_Float16*)(bsum + 256);            // H*8*4*64*8 halves
    _Float16* Wefrag  = Wfcfrag + NH * 8 * 4 * 64 * 8;      // H*2*4*64*8 halves
    size_t need = (size_t)((char*)(Wefrag + NH * 2 * 4 * 64 * 8) - (char*)d_ws);

    hipMemsetAsync(out, 0, (size_t)N_NODES * NH * OUT_F * sizeof(float), stream);

    if (ws_size < need) {
        // graceful finite-absmax failure instead of OOB fault (canary)
        hipMemsetAsync(ebuf, 0, (size_t)NH * N_EDGES * sizeof(float), stream);
        return;
    }

    prep_kernel<<<41 + SCAN_NB, 256, 0, stream>>>(W_att, b_att, W_eatt, b_eatt,
                                                  W_fc, W_edge, u, c,
                                                  Wfcfrag, Wefrag, deg);

    hist_kernel<<<(N_EDGES + 255) / 256, 256, 0, stream>>>(edge_index, deg);
    scan1_kernel<<<SCAN_NB, 256, 0, stream>>>(deg, row_ptr, bsum);
    scan2_kernel<<<1, 256, 0, stream>>>(bsum);
    scan3_kernel<<<SCAN_NB, 256, 0, stream>>>(bsum, row_ptr, cursor);
    scatter_kernel<<<(N_EDGES + 255) / 256, 256, 0, stream>>>(edge_index, cursor,
                                                              eorig, epos);
    fill_kernel<<<(N_EDGES + 255) / 256, 256, 0, stream>>>(edge_index, eorig,
                                                           ssrc, sdst);

    z_gemm<<<(N_NODES + 63) / 64, 256, 0, stream>>>(x, Wfcfrag, b_fc, W_att,
                                                    zb, a_i, a_j);

    logits_kernel<<<(N_EDGES + 255) / 256, 256, 0, stream>>>(ssrc, sdst, eorig, edge_attr,
                                                             u, c, a_i, a_j, epermT);

    softmax_kernel<<<SCAN_NB, 256, 0, stream>>>(row_ptr, epermT);

    alpha_orig_kernel<<<(N_EDGES + 255) / 256, 256, 0, stream>>>(epos, epermT, ebuf);

    aggregate_mfma<<<N_EDGES / 64, 256, 0, stream>>>(ssrc, sdst, eorig, edge_attr,
                                                     Wefrag, b_edge, zb, epermT, out);
}

// Round 8
// 429.866 us; speedup vs baseline: 1.2646x; 1.0006x over previous
//
#include <hip/hip_runtime.h>
#include <math.h>

#define N_NODES 50000
#define N_EDGES 400000
#define IN_F 256
#define OUT_F 64
#define ED_F 64
#define NH 4
#define SCAN_NB ((N_NODES + 255) / 256)

using f16x8 = __attribute__((ext_vector_type(8))) _Float16;
using f32x4 = __attribute__((ext_vector_type(4))) float;

// block 0: u[h][f] = sum_g W_eatt[h][f][g]*We[h][g]; c[h] = b_att[h] + b_eatt[h].We[h]
// blocks 1..32: Wfcfrag (f16, MFMA b-frag order), blocks 33..40: Wefrag
// blocks 41..236: zero deg (replaces a memset dispatch)
__global__ __launch_bounds__(256) void prep_kernel(
    const float* __restrict__ W_att, const float* __restrict__ b_att,
    const float* __restrict__ W_eatt, const float* __restrict__ b_eatt,
    const float* __restrict__ W_fc, const float* __restrict__ W_edge,
    float* __restrict__ u, float* __restrict__ c,
    _Float16* __restrict__ Wfcfrag, _Float16* __restrict__ Wefrag,
    int* __restrict__ deg)
{
    const int b = blockIdx.x, t = threadIdx.x;
    if (b == 0) {
        int h = t >> 6, f = t & 63;
        const float* We = W_att + h * (2 * OUT_F + ED_F) + 2 * OUT_F;
        float s = 0.f;
        for (int g = 0; g < ED_F; g++) s += W_eatt[(h * ED_F + f) * ED_F + g] * We[g];
        u[t] = s;
        if (f == 0) {
            float cc = b_att[h];
            for (int g = 0; g < ED_F; g++) cc += b_eatt[h * ED_F + g] * We[g];
            c[h] = cc;
        }
    } else if (b <= 32) {
        // b_frag[lane][j] = B[k=quad*8+j][n=lane&15], B = W_fc[h] (256x64)
        int idx = b - 1;
        int h = idx >> 3, kt = idx & 7;
        int lane = t & 63, nt = t >> 6;
        int q = lane >> 4, l15 = lane & 15;
        f16x8 w;
#pragma unroll
        for (int j = 0; j < 8; j++) {
            int k = kt * 32 + q * 8 + j;
            int o = nt * 16 + l15;
            w[j] = (_Float16)W_fc[((size_t)h * IN_F + k) * OUT_F + o];
        }
        *(f16x8*)&Wfcfrag[(size_t)(((h * 8 + kt) * 4 + nt) * 64 + lane) * 8] = w;
    } else if (b <= 40) {
        int idx = b - 33;
        int h = idx >> 1, kt = idx & 1;
        int lane = t & 63, nt = t >> 6;
        int q = lane >> 4, l15 = lane & 15;
        f16x8 w;
#pragma unroll
        for (int j = 0; j < 8; j++) {
            int k = kt * 32 + q * 8 + j;
            int o = nt * 16 + l15;
            w[j] = (_Float16)W_edge[((size_t)h * ED_F + k) * OUT_F + o];
        }
        *(f16x8*)&Wefrag[(size_t)(((h * 2 + kt) * 4 + nt) * 64 + lane) * 8] = w;
    } else {
        const int idx = (b - 41) * 256 + t;
        if (idx < N_NODES) deg[idx] = 0;
    }
}

// z[h][n][o] = x@W_fc + b_fc, f16 MFMA 16x16x32. Block: 64 nodes, 4 waves = 4 heads.
// Fused epilogue: a_i[h][n] = z.Wi, a_j[h][n] = z.Wj (computed from fp32 acc).
__global__ __launch_bounds__(256) void z_gemm(
    const float* __restrict__ x, const _Float16* __restrict__ Wfcfrag,
    const float* __restrict__ b_fc, const float* __restrict__ W_att,
    _Float16* __restrict__ zb, float* __restrict__ a_i, float* __restrict__ a_j)
{
    __shared__ _Float16 aLDS[32 * 64 * 8];   // 32 chunks(kt,quad) x 64 nodes x 8 f16 = 32KB
    const int t = threadIdx.x;
    const int n0 = blockIdx.x * 64;
    const int lane = t & 63, h = t >> 6;
    const int q = lane >> 4, l15 = lane & 15;

    // stage x tile (64 nodes x 256 k) fp32 -> f16 frag-order LDS
    {
        const int m = t >> 2, qq = t & 3;
        const int n = n0 + m;
#pragma unroll
        for (int p = 0; p < 4; p++) {
            float4 v4[4];
            if (n < N_NODES) {
                const float4* xp = (const float4*)(x + (size_t)n * IN_F + p * 64 + qq * 16);
#pragma unroll
                for (int k = 0; k < 4; k++) v4[k] = xp[k];
            } else {
#pragma unroll
                for (int k = 0; k < 4; k++) v4[k] = make_float4(0.f, 0.f, 0.f, 0.f);
            }
            const float* vv = (const float*)v4;
#pragma unroll
            for (int i = 0; i < 2; i++) {
                int c8 = p * 8 + qq * 2 + i;
                f16x8 w;
#pragma unroll
                for (int j = 0; j < 8; j++) w[j] = (_Float16)vv[i * 8 + j];
                *(f16x8*)&aLDS[(c8 * 64 + m) * 8] = w;
            }
        }
    }
    __syncthreads();

    f32x4 acc[4][4];
#pragma unroll
    for (int mt = 0; mt < 4; mt++)
#pragma unroll
        for (int nt = 0; nt < 4; nt++) acc[mt][nt] = (f32x4)0.f;

    for (int kt = 0; kt < 8; kt++) {
        f16x8 bfr[4];
#pragma unroll
        for (int nt = 0; nt < 4; nt++)
            bfr[nt] = *(const f16x8*)&Wfcfrag[(size_t)(((h * 8 + kt) * 4 + nt) * 64 + lane) * 8];
        f16x8 afr[4];
#pragma unroll
        for (int mt = 0; mt < 4; mt++)
            afr[mt] = *(f16x8*)&aLDS[((kt * 4 + q) * 64 + mt * 16 + l15) * 8];
#pragma unroll
        for (int mt = 0; mt < 4; mt++)
#pragma unroll
            for (int nt = 0; nt < 4; nt++)
                acc[mt][nt] = __builtin_amdgcn_mfma_f32_16x16x32_f16(afr[mt], bfr[nt], acc[mt][nt], 0, 0, 0);
    }

    float bfc[4], wiv[4], wjv[4];
#pragma unroll
    for (int nt = 0; nt < 4; nt++) {
        bfc[nt] = b_fc[h * OUT_F + nt * 16 + l15];
        wiv[nt] = W_att[h * 192 + nt * 16 + l15];
        wjv[nt] = W_att[h * 192 + 64 + nt * 16 + l15];
    }

    // C/D layout: col = lane&15, row = quad*4 + reg
#pragma unroll
    for (int mt = 0; mt < 4; mt++) {
#pragma unroll
        for (int r = 0; r < 4; r++) {
            const int node = n0 + mt * 16 + q * 4 + r;
            float zv[4];
            float pi = 0.f, pj = 0.f;
#pragma unroll
            for (int nt = 0; nt < 4; nt++) {
                zv[nt] = acc[mt][nt][r] + bfc[nt];
                pi += zv[nt] * wiv[nt];
                pj += zv[nt] * wjv[nt];
            }
            // reduce over the 16 l15 lanes (same q group -> same node)
#pragma unroll
            for (int m = 8; m; m >>= 1) {
                pi += __shfl_xor(pi, m, 64);
                pj += __shfl_xor(pj, m, 64);
            }
            if (node < N_NODES) {
                _Float16* zrow = zb + ((size_t)h * N_NODES + node) * OUT_F;
#pragma unroll
                for (int nt = 0; nt < 4; nt++)
                    zrow[nt * 16 + l15] = (_Float16)zv[nt];
                if (l15 == 0) {
                    a_i[h * N_NODES + node] = pi;
                    a_j[h * N_NODES + node] = pj;
                }
            }
        }
    }
}

// --- counting-sort by dst -------------------------------------------------

__global__ __launch_bounds__(256) void hist_kernel(
    const int* __restrict__ edge_index, int* __restrict__ deg)
{
    const int e = blockIdx.x * 256 + threadIdx.x;
    if (e < N_EDGES) atomicAdd(&deg[edge_index[N_EDGES + e]], 1);
}

// hierarchical scan phase 1: per-block exclusive scan + block totals
__global__ __launch_bounds__(256) void scan1_kernel(
    const int* __restrict__ deg, int* __restrict__ row_ptr, int* __restrict__ bsum)
{
    __shared__ int wsum[4];
    const int t = threadIdx.x, lane = t & 63, w = t >> 6;
    const int idx = blockIdx.x * 256 + t;
    int v = (idx < N_NODES) ? deg[idx] : 0;
    int x = v;
#pragma unroll
    for (int off = 1; off < 64; off <<= 1) {
        int y = __shfl_up(x, off, 64);
        if (lane >= off) x += y;
    }
    if (lane == 63) wsum[w] = x;
    __syncthreads();
    int woff = 0;
#pragma unroll
    for (int i = 0; i < 4; i++) if (i < w) woff += wsum[i];
    if (idx < N_NODES) row_ptr[idx] = woff + x - v;
    if (t == 255) bsum[blockIdx.x] = woff + x;
}

// phase 2: single block scans the <=256 block totals in place (exclusive)
__global__ __launch_bounds__(256) void scan2_kernel(int* __restrict__ bsum)
{
    __shared__ int wsum[4];
    const int t = threadIdx.x, lane = t & 63, w = t >> 6;
    int v = (t < SCAN_NB) ? bsum[t] : 0;
    int x = v;
#pragma unroll
    for (int off = 1; off < 64; off <<= 1) {
        int y = __shfl_up(x, off, 64);
        if (lane >= off) x += y;
    }
    if (lane == 63) wsum[w] = x;
    __syncthreads();
    int woff = 0;
#pragma unroll
    for (int i = 0; i < 4; i++) if (i < w) woff += wsum[i];
    __syncthreads();
    if (t < SCAN_NB) bsum[t] = woff + x - v;
}

// phase 3: add block offsets, produce cursor copy and row_ptr[N]
__global__ __launch_bounds__(256) void scan3_kernel(
    const int* __restrict__ bsum, int* __restrict__ row_ptr, int* __restrict__ cursor)
{
    const int idx = blockIdx.x * 256 + threadIdx.x;
    if (idx < N_NODES) {
        int rp = row_ptr[idx] + bsum[blockIdx.x];
        row_ptr[idx] = rp;
        cursor[idx] = rp;
    } else if (idx == N_NODES) {
        row_ptr[N_NODES] = N_EDGES;
    }
}

// scatter: eorig (random 4B) + epos (coalesced). ssrc/sdst built in logits (gather).
__global__ __launch_bounds__(256) void scatter_kernel(
    const int* __restrict__ edge_index, int* __restrict__ cursor,
    int* __restrict__ eorig, int* __restrict__ epos)
{
    const int e = blockIdx.x * 256 + threadIdx.x;
    if (e >= N_EDGES) return;
    const int d = edge_index[N_EDGES + e];
    const int pos = atomicAdd(&cursor[d], 1);
    eorig[pos] = e;
    epos[e] = pos;
}

// thread per sorted position p: all 4 head logits in registers, one float4 store.
// Also materializes ssrc/sdst (coalesced) for downstream kernels (fill fused in).
__global__ __launch_bounds__(256) void logits_kernel(
    const int* __restrict__ edge_index, const int* __restrict__ eorig,
    const float* __restrict__ edge_attr,
    const float* __restrict__ u, const float* __restrict__ c,
    const float* __restrict__ a_i, const float* __restrict__ a_j,
    int* __restrict__ ssrc, int* __restrict__ sdst,
    float4* __restrict__ epermT)
{
    __shared__ float uS[NH * ED_F];
    __shared__ float cS[NH];
    const int t = threadIdx.x;
    uS[t] = u[t];
    if (t < NH) cS[t] = c[t];
    __syncthreads();

    const int p = blockIdx.x * 256 + t;
    if (p >= N_EDGES) return;
    const int e = eorig[p];
    const int src = edge_index[e];
    const int dst = edge_index[N_EDGES + e];
    ssrc[p] = src;
    sdst[p] = dst;
    const float4* ap = (const float4*)(edge_attr + (size_t)e * ED_F);

    float acc[NH] = {0.f, 0.f, 0.f, 0.f};
#pragma unroll
    for (int j = 0; j < 16; j++) {
        const float4 v = ap[j];
#pragma unroll
        for (int h = 0; h < NH; h++) {
            const float4 uv = *(const float4*)&uS[h * ED_F + j * 4];
            acc[h] += v.x * uv.x + v.y * uv.y + v.z * uv.z + v.w * uv.w;
        }
    }
    float4 ev;
    float* evp = (float*)&ev;
#pragma unroll
    for (int h = 0; h < NH; h++) {
        float a = acc[h] + a_i[h * N_NODES + dst] + a_j[h * N_NODES + src] + cS[h];
        evp[h] = a > 0.f ? a : 0.2f * a;
    }
    epermT[p] = ev;
}

// per node: softmax over contiguous run, ALL 4 heads at once (float4).
// In-place logits -> alpha. No scatter (original-order output via gather kernel).
__global__ __launch_bounds__(256) void softmax_kernel(
    const int* __restrict__ row_ptr, float4* __restrict__ epermT)
{
    const int n = blockIdx.x * 256 + threadIdx.x;
    if (n >= N_NODES) return;
    const int b = row_ptr[n], en = row_ptr[n + 1];
    if (b >= en) return;

    float4 m4 = make_float4(-INFINITY, -INFINITY, -INFINITY, -INFINITY);
    for (int p = b; p < en; p++) {
        const float4 v = epermT[p];
        m4.x = fmaxf(m4.x, v.x); m4.y = fmaxf(m4.y, v.y);
        m4.z = fmaxf(m4.z, v.z); m4.w = fmaxf(m4.w, v.w);
    }
    float4 s4 = make_float4(0.f, 0.f, 0.f, 0.f);
    for (int p = b; p < en; p++) {
        const float4 v = epermT[p];
        s4.x += __expf(v.x - m4.x); s4.y += __expf(v.y - m4.y);
        s4.z += __expf(v.z - m4.z); s4.w += __expf(v.w - m4.w);
    }
    const float4 i4 = make_float4(1.f / s4.x, 1.f / s4.y, 1.f / s4.z, 1.f / s4.w);
    for (int p = b; p < en; p++) {
        const float4 v = epermT[p];
        epermT[p] = make_float4(__expf(v.x - m4.x) * i4.x, __expf(v.y - m4.y) * i4.y,
                                __expf(v.z - m4.z) * i4.z, __expf(v.w - m4.w) * i4.w);
    }
}

// alpha in ORIGINAL edge order: coalesced epos read + plane writes; random
// float4 gathers absorbed by L2/L3.
__global__ __launch_bounds__(256) void alpha_orig_kernel(
    const int* __restrict__ epos, const float4* __restrict__ epermT,
    float* __restrict__ ebuf)
{
    const int e = blockIdx.x * 256 + threadIdx.x;
    if (e >= N_EDGES) return;
    const float4 a = epermT[epos[e]];
    ebuf[e] = a.x;
    ebuf[(size_t)N_EDGES + e] = a.y;
    ebuf[(size_t)2 * N_EDGES + e] = a.z;
    ebuf[(size_t)3 * N_EDGES + e] = a.w;
}

// fused: ez = edge_attr@W_edge (f16 MFMA) + b_edge; msg = alpha*(z[src]+ez+be);
// dst-sorted segmented reduction. Interior runs (fully owned by this block)
// use PLAIN STORES; only the 2 boundary runs per (block,head) use atomics.
// 14.4M atomic dwords -> 3.2M: removes the L2 atomic-RMW drain.
__global__ __launch_bounds__(256) void aggregate_mfma(
    const int* __restrict__ ssrc, const int* __restrict__ sdst,
    const int* __restrict__ eorig, const float* __restrict__ edge_attr,
    const _Float16* __restrict__ Wefrag, const float* __restrict__ b_edge,
    const _Float16* __restrict__ zb, const float4* __restrict__ epermT,
    float* __restrict__ out)
{
    __shared__ float tbuf[NH * 16 * 66];     // 16896B; front 8KB doubles as f16 A-stage
    __shared__ int srcS[64], dstS[64];
    __shared__ float alphaS[NH][64];
    _Float16* aLDS = (_Float16*)tbuf;        // 8 chunks x 64 edges x 8 f16 = 8KB

    const int t = threadIdx.x;
    const int p0 = blockIdx.x * 64;
    const int lane = t & 63, h = t >> 6;
    const int q = lane >> 4, l15 = lane & 15;

    if (t < 64) srcS[t] = ssrc[p0 + t];
    else if (t < 128) dstS[t - 64] = sdst[p0 + t - 64];

    // alpha: each wave loads the block's 64 float4s (L1-hot across waves),
    // keeps its own head component. Wave-private alphaS row -> no barrier.
    {
        const float4 a4 = epermT[p0 + lane];
        alphaS[h][lane] = ((const float*)&a4)[h];
    }

    // stage edge_attr rows (gathered via eorig) fp32 -> f16 frag-order LDS
    {
        const int m = t >> 2, qq = t & 3;
        const int er = eorig[p0 + m];
        const float4* ap = (const float4*)(edge_attr + (size_t)er * ED_F + qq * 16);
        float4 v4[4];
#pragma unroll
        for (int k = 0; k < 4; k++) v4[k] = ap[k];
        const float* vv = (const float*)v4;
#pragma unroll
        for (int i = 0; i < 2; i++) {
            int c8 = qq * 2 + i;
            f16x8 w;
#pragma unroll
            for (int j = 0; j < 8; j++) w[j] = (_Float16)vv[i * 8 + j];
            *(f16x8*)&aLDS[(c8 * 64 + m) * 8] = w;
        }
    }
    __syncthreads();

    f16x8 wf[2][4];
#pragma unroll
    for (int kt = 0; kt < 2; kt++)
#pragma unroll
        for (int nt = 0; nt < 4; nt++)
            wf[kt][nt] = *(const f16x8*)&Wefrag[(size_t)(((h * 2 + kt) * 4 + nt) * 64 + lane) * 8];

    f32x4 acc[4][4];
#pragma unroll
    for (int mt = 0; mt < 4; mt++)
#pragma unroll
        for (int nt = 0; nt < 4; nt++) acc[mt][nt] = (f32x4)0.f;

#pragma unroll
    for (int kt = 0; kt < 2; kt++) {
        f16x8 afr[4];
#pragma unroll
        for (int mt = 0; mt < 4; mt++)
            afr[mt] = *(f16x8*)&aLDS[((kt * 4 + q) * 64 + mt * 16 + l15) * 8];
#pragma unroll
        for (int mt = 0; mt < 4; mt++)
#pragma unroll
            for (int nt = 0; nt < 4; nt++)
                acc[mt][nt] = __builtin_amdgcn_mfma_f32_16x16x32_f16(afr[mt], wf[kt][nt], acc[mt][nt], 0, 0, 0);
    }

    __syncthreads();   // all waves done reading aLDS before tbuf overwrites it

    const float beL = b_edge[h * OUT_F + lane];
    float* tb = &tbuf[h * 16 * 66];
    int cur = dstS[0];
    float accv = 0.f;
    bool first = true;   // first run may be shared with the previous block

    // per-quarter transpose + zf prefetch + segmented reduce (wave-private)
#pragma unroll
    for (int mt = 0; mt < 4; mt++) {
#pragma unroll
        for (int r = 0; r < 4; r++)
#pragma unroll
            for (int nt = 0; nt < 4; nt++)
                tb[(q * 4 + r) * 66 + nt * 16 + l15] = acc[mt][nt][r];

        // prefetch the 16 z[src] gathers for this quarter (static unroll -> regs)
        float zf[16];
#pragma unroll
        for (int i = 0; i < 16; i++)
            zf[i] = (float)zb[((size_t)h * N_NODES + srcS[mt * 16 + i]) * OUT_F + lane];

#pragma unroll
        for (int i = 0; i < 16; i++) {
            const int el = mt * 16 + i;
            const int d = dstS[el];
            const float msg = tb[i * 66 + lane];
            if (d != cur) {
                float* orow = &out[(size_t)cur * (NH * OUT_F) + h * OUT_F + lane];
                if (first) atomicAdd(orow, accv);
                else       *orow = accv;          // interior run: block-exclusive
                first = false;
                accv = 0.f;
                cur = d;
            }
            accv += alphaS[h][el] * (msg + beL + zf[i]);
        }
    }
    // last run may continue into the next block -> atomic
    atomicAdd(&out[(size_t)cur * (NH * OUT_F) + h * OUT_F + lane], accv);
}

extern "C" void kernel_launch(void* const* d_in, const int* in_sizes, int n_in,
                              void* d_out, int out_size, void* d_ws, size_t ws_size,
                              hipStream_t stream) {
    const float* x         = (const float*)d_in[0];
    const int*   edge_index= (const int*)  d_in[1];
    const float* edge_attr = (const float*)d_in[2];
    const float* W_fc      = (const float*)d_in[3];
    const float* b_fc      = (const float*)d_in[4];
    const float* W_att     = (const float*)d_in[5];
    const float* b_att     = (const float*)d_in[6];
    const float* W_edge    = (const float*)d_in[7];
    const float* b_edge    = (const float*)d_in[8];
    const float* W_eatt    = (const float*)d_in[9];
    const float* b_eatt    = (const float*)d_in[10];

    float* out  = (float*)d_out;                          // (N, H*OUT)
    float* ebuf = out + (size_t)N_NODES * NH * OUT_F;     // (H, E): alpha (original order)

    // ws layout (epermT first after zb to keep 16B alignment)
    _Float16* zb   = (_Float16*)d_ws;                       // NH*N*64 f16 = 25.6MB
    float4* epermT = (float4*)(zb + (size_t)NH * N_NODES * OUT_F);  // E float4 = 6.4MB
    float* a_i     = (float*)(epermT + N_EDGES);
    float* a_j     = a_i + NH * N_NODES;
    float* u       = a_j + NH * N_NODES;                    // H*64
    float* c       = u + NH * 64;                           // H
    int* deg       = (int*)(c + NH);
    int* cursor    = deg + N_NODES;
    int* row_ptr   = cursor + N_NODES;                      // N+1 used, N+16 reserved
    int* epos      = row_ptr + (N_NODES + 16);
    int* eorig     = epos + N_EDGES;
    int* ssrc      = eorig + N_EDGES;
    int* sdst      = ssrc + N_EDGES;
    int* bsum      = sdst + N_EDGES;                        // 256 ints
    _Float16* Wfcfrag = (_Float16*)(bsum + 256);            // H*8*4*64*8 halves
    _Float16* Wefrag  = Wfcfrag + NH * 8 * 4 * 64 * 8;      // H*2*4*64*8 halves
    size_t need = (size_t)((char*)(Wefrag + NH * 2 * 4 * 64 * 8) - (char*)d_ws);

    hipMemsetAsync(out, 0, (size_t)N_NODES * NH * OUT_F * sizeof(float), stream);

    if (ws_size < need) {
        // graceful finite-absmax failure instead of OOB fault (canary)
        hipMemsetAsync(ebuf, 0, (size_t)NH * N_EDGES * sizeof(float), stream);
        return;
    }

    prep_kernel<<<41 + SCAN_NB, 256, 0, stream>>>(W_att, b_att, W_eatt, b_eatt,
                                                  W_fc, W_edge, u, c,
                                                  Wfcfrag, Wefrag, deg);

    hist_kernel<<<(N_EDGES + 255) / 256, 256, 0, stream>>>(edge_index, deg);
    scan1_kernel<<<SCAN_NB, 256, 0, stream>>>(deg, row_ptr, bsum);
    scan2_kernel<<<1, 256, 0, stream>>>(bsum);
    scan3_kernel<<<SCAN_NB, 256, 0, stream>>>(bsum, row_ptr, cursor);
    scatter_kernel<<<(N_EDGES + 255) / 256, 256, 0, stream>>>(edge_index, cursor,
                                                              eorig, epos);

    z_gemm<<<(N_NODES + 63) / 64, 256, 0, stream>>>(x, Wfcfrag, b_fc, W_att,
                                                    zb, a_i, a_j);

    logits_kernel<<<(N_EDGES + 255) / 256, 256, 0, stream>>>(edge_index, eorig, edge_attr,
                                                             u, c, a_i, a_j,
                                                             ssrc, sdst, epermT);

    softmax_kernel<<<SCAN_NB, 256, 0, stream>>>(row_ptr, epermT);

    alpha_orig_kernel<<<(N_EDGES + 255) / 256, 256, 0, stream>>>(epos, epermT, ebuf);

    aggregate_mfma<<<N_EDGES / 64, 256, 0, stream>>>(ssrc, sdst, eorig, edge_attr,
                                                     Wefrag, b_edge, zb, epermT, out);
}